// Round 7
// baseline (301.354 us; speedup 1.0000x reference)
//
#include <hip/hip_runtime.h>
#include <stdint.h>

// MRICls fused kernel for MI355X (gfx950) — round 7.
// feat = [F0*g, F1*g, S0*g, S1*g] (464) -> 64 -> 32 -> 2 -> softmax, B=131072.
// g = sigmoid(0.25*(F0+F1)*(S0+S1)) elementwise in j.
//
// Block = 32 rows / 128 threads / 2 waves. Staging: wave0 copies the block's F
// span (32 rows x 928 B = 29696 B = EXACTLY 29 contiguous 1-KB gll), wave1 the S
// span. One vmcnt(0) + one barrier, then the K-loop is pure LDS + L2-B, barrier-
// free. Gate is fully IN-LANE: x-pair (own family) + y-pair (other family) read
// from LDS (4-way bank conflict only), u = x0+x1, v = y0+y1, g = sigmoid(.25uv).
// K-permutation unchanged from r4-r6 (W1 prepped identically):
//   k' = 32t + 8h + 2jp + s <-> family=(h>=2?S:F), seg=s, j = 8t + 4*(h&1) + jp
// Pad j>=116 (t=14, odd h) multiplies ZEROED W1 rows -> any finite A is correct.
// ws: 61440 B (W1 fp16 fragment-direct, permuted).

typedef float    f4    __attribute__((ext_vector_type(4)));
typedef float    f32x4 __attribute__((ext_vector_type(4)));
typedef _Float16 h8    __attribute__((ext_vector_type(8)));

#define NSTEP 15

// ---- prep: W1[116*(2*fam+s) + j][n] -> Wsp[t][n 64][kk 32] fp16, permuted K ----
__global__ void prep_w1(const float* __restrict__ W1, _Float16* __restrict__ Wsp) {
  const int e  = blockIdx.x * 256 + threadIdx.x;   // 0..30719
  const int t  = e >> 11;
  const int r  = e & 2047;
  const int n  = r & 63;
  const int kk = r >> 6;          // 0..31
  const int h  = kk >> 3;         // 0..3
  const int ee = kk & 7;
  const int s  = ee & 1;
  const int jp = ee >> 1;         // 0..3
  const int fam = h >> 1;         // 0 = F, 1 = S
  const int j  = 8 * t + 4 * (h & 1) + jp;
  const int ko = 232 * fam + 116 * s + j;
  const float v = (j < 116) ? W1[ko * 64 + n] : 0.f;
  Wsp[t * 2048 + n * 32 + kk] = (_Float16)v;
}

__global__ __launch_bounds__(128, 2) void mricls_main(
    const float* __restrict__ F, const float* __restrict__ S,
    const float* __restrict__ b1, const float* __restrict__ W2,
    const float* __restrict__ b2, const float* __restrict__ W3,
    const float* __restrict__ b3, const _Float16* __restrict__ Wsp,
    float* __restrict__ out) {
  // Raw row-major F/S spans; h1 overlays the (dead-after-K-loop) F region.
  __shared__ __align__(16) union {
    struct { char f[29696]; char s[29696]; } buf;   // 59392 B
    float h1[32][68];                               //  8704 B (inside f)
  } U;
  __shared__ __align__(16) float W2s[64][32];
  __shared__ __align__(16) float W3s[32][2];
  __shared__ __align__(16) float b1s[64];
  __shared__ __align__(16) float b2s[32];
  __shared__ float b3s[2];

  const int tid = threadIdx.x;   // 0..127
  const int l   = tid & 63;
  const int w   = tid >> 6;      // wave 0 = F-stager, 1 = S-stager
  const int ml  = l & 15;        // A row / B col
  const int h   = l >> 4;        // k-group: 0,1 = F-pairs, 2,3 = S-pairs

  // ---- staging FIRST: 29 contiguous 1-KB gll per wave (lane L -> base+16L) ----
  {
    const char* gsrc = ((w == 0) ? (const char*)F : (const char*)S)
                       + (size_t)blockIdx.x * 29696 + l * 16;
    char* ldst = (w == 0) ? U.buf.f : U.buf.s;
#pragma unroll
    for (int g = 0; g < 29; ++g)
      __builtin_amdgcn_global_load_lds(gsrc + g * 1024, ldst + g * 1024, 16, 0, 0);
  }

  // ---- small weights to LDS (flies during gll wait) ----
  {
    const f4* W2v = (const f4*)W2;
    f4* W2sv = (f4*)W2s;
#pragma unroll
    for (int i = 0; i < 4; ++i) W2sv[tid + 128 * i] = W2v[tid + 128 * i];
    if (tid < 16) ((f4*)W3s)[tid] = ((const f4*)W3)[tid];
    if (tid < 16) ((f4*)b1s)[tid] = ((const f4*)b1)[tid];
    if (tid < 8)  ((f4*)b2s)[tid] = ((const f4*)b2)[tid];
    if (tid < 2)  b3s[tid] = b3[tid];
  }

  // ---- B prologue (t=0) — L2-hot after first blocks; flies during gll wait ----
  const char* bb = (const char*)Wsp + ml * 64 + h * 16;  // + t*4096 + nt*1024
  h8 bq[2][4];
#pragma unroll
  for (int nt = 0; nt < 4; ++nt) bq[0][nt] = *(const h8*)(bb + nt * 1024);

  asm volatile("s_waitcnt vmcnt(0)" ::: "memory");
  __syncthreads();   // both spans + W2s visible to both waves

  // ---- K-loop: per-wave rows w*16..w*16+15; pure LDS + reg-B; barrier-free ----
  const int r  = w * 16 + ml;
  const int fam = h >> 1;
  const char* xb = (fam ? U.buf.s : U.buf.f) + r * 928 + (h & 1) * 16;  // own family
  const char* yb = (fam ? U.buf.f : U.buf.s) + r * 928 + (h & 1) * 16;  // other family

  f32x4 acc[4];
#pragma unroll
  for (int nt = 0; nt < 4; ++nt) acc[nt] = (f32x4){0.f, 0.f, 0.f, 0.f};

#pragma unroll
  for (int t = 0; t < NSTEP; ++t) {
    if (t + 1 < NSTEP) {   // B double-buffer: load t+1 while computing t
#pragma unroll
      for (int nt = 0; nt < 4; ++nt)
        bq[(t + 1) & 1][nt] = *(const h8*)(bb + (t + 1) * 4096 + nt * 1024);
    }
    const f4 x0 = *(const f4*)(xb + t * 32);         // own seg0 @ j
    const f4 x1 = *(const f4*)(xb + t * 32 + 464);   // own seg1 @ j
    const f4 y0 = *(const f4*)(yb + t * 32);         // other seg0 @ j
    const f4 y1 = *(const f4*)(yb + t * 32 + 464);   // other seg1 @ j
    h8 a;
#pragma unroll
    for (int jp = 0; jp < 4; ++jp) {
      const float u = x0[jp] + x1[jp];               // own family sum
      const float v = y0[jp] + y1[jp];               // other family sum (in-lane!)
      const float g = 1.f / (1.f + __expf(-0.25f * u * v));
      a[2 * jp]     = (_Float16)(x0[jp] * g);
      a[2 * jp + 1] = (_Float16)(x1[jp] * g);
    }
#pragma unroll
    for (int nt = 0; nt < 4; ++nt)
      acc[nt] = __builtin_amdgcn_mfma_f32_16x16x32_f16(a, bq[t & 1][nt], acc[nt], 0, 0, 0);
  }

  __syncthreads();   // both waves done reading buf -> h1 overlay region live

  // ---- epilogue: h1 = relu(acc + b1) -> LDS (each wave writes its own rows) ----
#pragma unroll
  for (int nt = 0; nt < 4; ++nt) {
    const int n = nt * 16 + ml;
    const float bias = b1s[n];
#pragma unroll
    for (int rr = 0; rr < 4; ++rr) {
      const int mm = w * 16 + h * 4 + rr;  // C/D: col=lane&15, row=(lane>>4)*4+reg
      U.h1[mm][n] = fmaxf(acc[nt][rr] + bias, 0.f);
    }
  }
  // each wave reads back only its own rows (tid>>2 stays in-wave) -> no barrier

  // ---- layers 2,3 + softmax (fp32 VALU; 4 threads per row, 32 rows) ----
  const int m2 = tid >> 2;  // row 0..31
  const int q  = tid & 3;   // 8 h2-outputs each
  float acc2[8];
#pragma unroll
  for (int e = 0; e < 8; ++e) acc2[e] = b2s[q * 8 + e];
#pragma unroll 8
  for (int k = 0; k < 64; ++k) {
    const float hk = U.h1[m2][k];
    const f4 w0 = *(const f4*)&W2s[k][q * 8];
    const f4 w1 = *(const f4*)&W2s[k][q * 8 + 4];
    acc2[0] = fmaf(hk, w0[0], acc2[0]);
    acc2[1] = fmaf(hk, w0[1], acc2[1]);
    acc2[2] = fmaf(hk, w0[2], acc2[2]);
    acc2[3] = fmaf(hk, w0[3], acc2[3]);
    acc2[4] = fmaf(hk, w1[0], acc2[4]);
    acc2[5] = fmaf(hk, w1[1], acc2[5]);
    acc2[6] = fmaf(hk, w1[2], acc2[6]);
    acc2[7] = fmaf(hk, w1[3], acc2[7]);
  }
  float p0 = 0.f, p1 = 0.f;
#pragma unroll
  for (int e = 0; e < 8; ++e) {
    const float hv = fmaxf(acc2[e], 0.f);
    p0 = fmaf(hv, W3s[q * 8 + e][0], p0);
    p1 = fmaf(hv, W3s[q * 8 + e][1], p1);
  }
  p0 += __shfl_xor(p0, 1); p0 += __shfl_xor(p0, 2);
  p1 += __shfl_xor(p1, 1); p1 += __shfl_xor(p1, 2);
  if (q == 0) {
    const float l0 = p0 + b3s[0], l1 = p1 + b3s[1];
    const float mx = fmaxf(l0, l1);
    const float e0 = __expf(l0 - mx), e1 = __expf(l1 - mx);
    const float inv = 1.f / (e0 + e1);
    float2 o = make_float2(e0 * inv, e1 * inv);
    *(float2*)(out + ((long)blockIdx.x * 32 + m2) * 2) = o;
  }
}

extern "C" void kernel_launch(void* const* d_in, const int* in_sizes, int n_in,
                              void* d_out, int out_size, void* d_ws, size_t ws_size,
                              hipStream_t stream) {
  const float* F  = (const float*)d_in[0];
  const float* S  = (const float*)d_in[1];
  const float* W1 = (const float*)d_in[2];
  const float* b1 = (const float*)d_in[3];
  const float* W2 = (const float*)d_in[4];
  const float* b2 = (const float*)d_in[5];
  const float* W3 = (const float*)d_in[6];
  const float* b3 = (const float*)d_in[7];
  _Float16* Wsp = (_Float16*)d_ws;   // needs 61440 B
  float* out = (float*)d_out;
  const int B = in_sizes[0] / 232;   // 131072

  prep_w1<<<dim3(120), dim3(256), 0, stream>>>(W1, Wsp);
  mricls_main<<<dim3(B / 32), dim3(128), 0, stream>>>(F, S, b1, W2, b2, W3, b3,
                                                      (const _Float16*)Wsp, out);
}

// Round 8
// 276.954 us; speedup vs baseline: 1.0881x; 1.0881x over previous
//
#include <hip/hip_runtime.h>
#include <stdint.h>

// MRICls fused kernel for MI355X (gfx950) — round 8.
// feat = [F0*g, F1*g, S0*g, S1*g] (464) -> 64 -> 32 -> 2 -> softmax, B=131072.
// g = sigmoid(0.25*(F0+F1)*(S0+S1)) elementwise in j.
//
// PERSISTENT GRID-STRIDE TILE PIPELINE (the fix for r6/r7's duty-cycle collapse):
// 512 blocks x 16 tiles of 16 rows. Iteration i: issue tile(i+1) loads (asm-pinned)
// -> MFMA(i) from LDS buf[i&1] -> h1 -> barrier -> MLP+softmax+store(i) ->
// vmcnt(0) -> gate+fp16 fragment ds_write buf[(i+1)&1] -> barrier. Stage-to-use
// distance = one full tile compute >> HBM latency; every wave keeps ~8 KB in
// flight continuously; 8 waves/CU.
// B (W1 frags) is TILE-INVARIANT: preloaded once, 15 h8 = 60 VGPR per wave
// (its 16-col slice). K-loop = 15 x (ds_read_b128 + MFMA), zero global traffic.
// Gate computed at stage time fully in-thread (loader holds F0,F1,S0,S1 quads).
// K-permutation unchanged from r4-r7 (W1 prepped identically):
//   k' = 32t + 8h + 2jp + s <-> fam=(h>>1), seg=s, j = 8t + 4*(h&1) + jp
// A-tile LDS: [t 15][row 16][80 B] (20-dword row stride -> bank-clean);
// row layout: [F-even 16B][F-odd 16B][S-even 16B][S-odd 16B][pad 16B].
// t=14 odd regions (j>=116) zeroed once at start, never rewritten; W1 also
// zeroed there (double protection).

typedef float    f4    __attribute__((ext_vector_type(4)));
typedef float    f32x4 __attribute__((ext_vector_type(4)));
typedef _Float16 h8    __attribute__((ext_vector_type(8)));
typedef int      i4    __attribute__((ext_vector_type(4)));

#define NSTEP 15
#define TPB   16     // tiles per block
#define BUFB  19200  // 15*16*80

// ---- prep: W1[116*(2*fam+s) + j][n] -> Wsp[t][n 64][kk 32] fp16, permuted K ----
__global__ void prep_w1(const float* __restrict__ W1, _Float16* __restrict__ Wsp) {
  const int e  = blockIdx.x * 256 + threadIdx.x;   // 0..30719
  const int t  = e >> 11;
  const int r  = e & 2047;
  const int n  = r & 63;
  const int kk = r >> 6;          // 0..31
  const int h  = kk >> 3;         // 0..3
  const int ee = kk & 7;
  const int s  = ee & 1;
  const int jp = ee >> 1;         // 0..3
  const int fam = h >> 1;         // 0 = F, 1 = S
  const int j  = 8 * t + 4 * (h & 1) + jp;
  const int ko = 232 * fam + 116 * s + j;
  const float v = (j < 116) ? W1[ko * 64 + n] : 0.f;
  Wsp[t * 2048 + n * 32 + kk] = (_Float16)v;
}

// asm-pinned 16-B global load (cannot be sunk past barriers / reordered)
#define BL(dst, addr, imm)                                                  \
  asm volatile("global_load_dwordx4 %0, %1, off offset:" #imm               \
               : "=v"(dst) : "v"(addr));

__global__ __launch_bounds__(256, 2) void mricls_main(
    const float* __restrict__ F, const float* __restrict__ S,
    const float* __restrict__ b1, const float* __restrict__ W2,
    const float* __restrict__ b2, const float* __restrict__ W3,
    const float* __restrict__ b3, const _Float16* __restrict__ Wsp,
    float* __restrict__ out) {
  __shared__ __align__(16) char  bufs[2 * BUFB];   // 38400 B A-fragment tiles
  __shared__ __align__(16) float h1s[16][68];      // 4352 B
  __shared__ __align__(16) float W2s[64][32];      // 8192 B
  __shared__ __align__(16) float W3s[32][2];
  __shared__ __align__(16) float b1s[64];
  __shared__ __align__(16) float b2s[32];
  __shared__ float b3s[2];

  const int tid = threadIdx.x;
  const int l   = tid & 63;
  const int w   = tid >> 6;      // wave 0..3 = output-column quad
  const int ml  = l & 15;
  const int h   = l >> 4;

  // ---- small weights -> LDS ----
  {
    const f4* W2v = (const f4*)W2;
    f4* W2sv = (f4*)W2s;
#pragma unroll
    for (int i = 0; i < 2; ++i) W2sv[tid + 256 * i] = W2v[tid + 256 * i];
    if (tid < 16) ((f4*)W3s)[tid] = ((const f4*)W3)[tid];
    if (tid < 16) ((f4*)b1s)[tid] = ((const f4*)b1)[tid];
    if (tid < 8)  ((f4*)b2s)[tid] = ((const f4*)b2)[tid];
    if (tid < 2)  b3s[tid] = b3[tid];
  }
  // ---- zero t=14 odd-j regions of BOTH buffers (never rewritten) ----
  if (tid < 64) {
    const int buf = tid >> 5, off16 = (tid >> 4) & 1, rr = tid & 15;
    *(f4*)(bufs + buf * BUFB + 14 * 1280 + rr * 80 + 16 + off16 * 32) =
        (f4){0.f, 0.f, 0.f, 0.f};
  }

  // ---- B preload: tile-invariant, 15 h8 = 60 VGPR (this wave's 16 cols) ----
  h8 bB[NSTEP];
  {
    const char* bb = (const char*)Wsp + (w * 16 + ml) * 64 + h * 16;
#pragma unroll
    for (int t = 0; t < NSTEP; ++t) bB[t] = *(const h8*)(bb + t * 4096);
  }

  // ---- stage-thread mapping: row = tid>>4 (0..15), c = tid&15 ----
  const int srow = tid >> 4;
  const int c    = tid & 15;
  // quads q1 = c (always), q2 = c+16 (only c<=12); c>12 duplicates q1 (safe addr)
  const float* fc  = F + ((long)blockIdx.x * 256 + srow) * 232 + 4 * c;
  const float* sc  = S + ((long)blockIdx.x * 256 + srow) * 232 + 4 * c;
  const float* fc2 = fc + ((c <= 12) ? 64 : 0);
  const float* sc2 = sc + ((c <= 12) ? 64 : 0);

  // gate+pack+write one quad's 16 gated fp16 values
#define STAGE_QUAD(bufW, q, f0, f1, s0, s1)                                    \
  {                                                                            \
    char* wb = (bufW) + ((q) >> 1) * 1280 + srow * 80 + ((q) & 1) * 16;        \
    h8 fa, sa;                                                                 \
    _Pragma("unroll")                                                          \
    for (int jp = 0; jp < 4; ++jp) {                                           \
      const float u  = f0[jp] + f1[jp];                                        \
      const float vv = s0[jp] + s1[jp];                                        \
      const float g  = 1.f / (1.f + __expf(-0.25f * u * vv));                  \
      fa[2 * jp]     = (_Float16)(f0[jp] * g);                                 \
      fa[2 * jp + 1] = (_Float16)(f1[jp] * g);                                 \
      sa[2 * jp]     = (_Float16)(s0[jp] * g);                                 \
      sa[2 * jp + 1] = (_Float16)(s1[jp] * g);                                 \
    }                                                                          \
    *(h8*)(wb)      = fa;                                                      \
    *(h8*)(wb + 32) = sa;                                                      \
  }

  // ---- prologue: stage tile 0 into buf0 ----
  {
    i4 rA, rB, rC, rD, rE, rF_, rG, rH;
    BL(rA, fc, 0) BL(rB, fc, 464) BL(rC, sc, 0) BL(rD, sc, 464)
    BL(rE, fc2, 0) BL(rF_, fc2, 464) BL(rG, sc2, 0) BL(rH, sc2, 464)
    asm volatile("s_waitcnt vmcnt(0)" ::: "memory");
    __builtin_amdgcn_sched_barrier(0);
    const f4 f0 = __builtin_bit_cast(f4, rA), f1 = __builtin_bit_cast(f4, rB);
    const f4 s0 = __builtin_bit_cast(f4, rC), s1 = __builtin_bit_cast(f4, rD);
    STAGE_QUAD(bufs, c, f0, f1, s0, s1)
    if (c <= 12) {
      const f4 g0 = __builtin_bit_cast(f4, rE), g1 = __builtin_bit_cast(f4, rF_);
      const f4 t0 = __builtin_bit_cast(f4, rG), t1 = __builtin_bit_cast(f4, rH);
      STAGE_QUAD(bufs, c + 16, g0, g1, t0, t1)
    }
  }
  __syncthreads();

  const int aoff = ml * 80 + h * 16;   // MFMA A-fragment lane offset

  // ---- persistent tile loop ----
#pragma unroll 2
  for (int i = 0; i < TPB; ++i) {
    // 1) issue tile(i+1) loads (asm-pinned; in flight across all of (i)'s work)
    i4 rA, rB, rC, rD, rE, rF_, rG, rH;
    if (i + 1 < TPB) {
      const float* nfc  = fc  + (i + 1) * 3712;   // 16 rows * 232 floats
      const float* nsc  = sc  + (i + 1) * 3712;
      const float* nfc2 = fc2 + (i + 1) * 3712;
      const float* nsc2 = sc2 + (i + 1) * 3712;
      BL(rA, nfc, 0) BL(rB, nfc, 464) BL(rC, nsc, 0) BL(rD, nsc, 464)
      BL(rE, nfc2, 0) BL(rF_, nfc2, 464) BL(rG, nsc2, 0) BL(rH, nsc2, 464)
    }

    // 2) MFMA tile i: 15 x (ds_read_b128 + mfma), B all-register
    const char* bufR = bufs + (i & 1) * BUFB;
    f32x4 acc = (f32x4){0.f, 0.f, 0.f, 0.f};
#pragma unroll
    for (int t = 0; t < NSTEP; ++t) {
      const h8 a = *(const h8*)(bufR + t * 1280 + aoff);
      acc = __builtin_amdgcn_mfma_f32_16x16x32_f16(a, bB[t], acc, 0, 0, 0);
    }

    // 3) h1 = relu(acc + b1)
    {
      const int n = w * 16 + ml;
      const float bias = b1s[n];
#pragma unroll
      for (int r = 0; r < 4; ++r)
        h1s[h * 4 + r][n] = fmaxf(acc[r] + bias, 0.f);
    }
    __syncthreads();

    // 4) MLP layers 2,3 + softmax + store (16 threads per row)
    {
      const int mrow = tid >> 4;    // 0..15
      const int u    = tid & 15;    // 2 h2-outputs each
      float a0 = b2s[2 * u], a1 = b2s[2 * u + 1];
#pragma unroll 8
      for (int k = 0; k < 64; ++k) {
        const float hk = h1s[mrow][k];
        const float2 w2 = *(const float2*)&W2s[k][2 * u];
        a0 = fmaf(hk, w2.x, a0);
        a1 = fmaf(hk, w2.y, a1);
      }
      const float hv0 = fmaxf(a0, 0.f), hv1 = fmaxf(a1, 0.f);
      float p0 = hv0 * W3s[2 * u][0] + hv1 * W3s[2 * u + 1][0];
      float p1 = hv0 * W3s[2 * u][1] + hv1 * W3s[2 * u + 1][1];
      p0 += __shfl_xor(p0, 1); p0 += __shfl_xor(p0, 2);
      p0 += __shfl_xor(p0, 4); p0 += __shfl_xor(p0, 8);
      p1 += __shfl_xor(p1, 1); p1 += __shfl_xor(p1, 2);
      p1 += __shfl_xor(p1, 4); p1 += __shfl_xor(p1, 8);
      if (u == 0) {
        const float l0 = p0 + b3s[0], l1 = p1 + b3s[1];
        const float mx = fmaxf(l0, l1);
        const float e0 = __expf(l0 - mx), e1 = __expf(l1 - mx);
        const float inv = 1.f / (e0 + e1);
        *(float2*)(out + ((long)blockIdx.x * 256 + i * 16 + mrow) * 2) =
            make_float2(e0 * inv, e1 * inv);
      }
    }

    // 5) gate + fragment-write tile i+1 into buf[(i+1)&1]
    if (i + 1 < TPB) {
      asm volatile("s_waitcnt vmcnt(0)" ::: "memory");
      __builtin_amdgcn_sched_barrier(0);
      char* bufW = bufs + ((i + 1) & 1) * BUFB;
      const f4 f0 = __builtin_bit_cast(f4, rA), f1 = __builtin_bit_cast(f4, rB);
      const f4 s0 = __builtin_bit_cast(f4, rC), s1 = __builtin_bit_cast(f4, rD);
      STAGE_QUAD(bufW, c, f0, f1, s0, s1)
      if (c <= 12) {
        const f4 g0 = __builtin_bit_cast(f4, rE), g1 = __builtin_bit_cast(f4, rF_);
        const f4 t0 = __builtin_bit_cast(f4, rG), t1 = __builtin_bit_cast(f4, rH);
        STAGE_QUAD(bufW, c + 16, g0, g1, t0, t1)
      }
    }
    __syncthreads();
  }
}

extern "C" void kernel_launch(void* const* d_in, const int* in_sizes, int n_in,
                              void* d_out, int out_size, void* d_ws, size_t ws_size,
                              hipStream_t stream) {
  const float* F  = (const float*)d_in[0];
  const float* S  = (const float*)d_in[1];
  const float* W1 = (const float*)d_in[2];
  const float* b1 = (const float*)d_in[3];
  const float* W2 = (const float*)d_in[4];
  const float* b2 = (const float*)d_in[5];
  const float* W3 = (const float*)d_in[6];
  const float* b3 = (const float*)d_in[7];
  _Float16* Wsp = (_Float16*)d_ws;   // needs 61440 B
  float* out = (float*)d_out;
  const int B = in_sizes[0] / 232;   // 131072

  prep_w1<<<dim3(120), dim3(256), 0, stream>>>(W1, Wsp);
  mricls_main<<<dim3(B / 256), dim3(256), 0, stream>>>(F, S, b1, W2, b2, W3, b3,
                                                       (const _Float16*)Wsp, out);
}